// Round 1
// baseline (1196.914 us; speedup 1.0000x reference)
//
#include <hip/hip_runtime.h>
#include <math.h>

#define NN 100000
#define NE 1600000

__device__ __forceinline__ float relu_f(float v) { return fmaxf(v, 0.0f); }

// out[j][k] = in[k][j], 64x64
__global__ void transpose64(const float* __restrict__ in, float* __restrict__ out) {
    int j = blockIdx.x, k = threadIdx.x;
    out[j * 64 + k] = in[k * 64 + j];
}

__global__ void init_kernel(const float* __restrict__ x, float* __restrict__ xw,
                            float* __restrict__ counts, float* __restrict__ agg) {
    int i = blockIdx.x * blockDim.x + threadIdx.x;
    if (i < NN) {
#pragma unroll
        for (int j = 0; j < 5; j++) {
            xw[i * 5 + j] = x[i * 5 + j];
            agg[i * 5 + j] = 0.0f;
        }
        counts[i] = 0.0f;
    }
}

__global__ void count_kernel(const int* __restrict__ dst, float* __restrict__ counts) {
    int e = blockIdx.x * blockDim.x + threadIdx.x;  // NE divisible by 256: no guard
    atomicAdd(&counts[dst[e]], 1.0f);
}

// EdgeModel + scatter-sum into agg. NE = 6250*256 exactly -> no guard, weight
// loads stay in uniform control flow (s_load path).
__global__ void edge_kernel(const float* __restrict__ xw, const float* __restrict__ edge_attr,
                            const int* __restrict__ src_idx, const int* __restrict__ dst_idx,
                            const float* __restrict__ ew1, const float* __restrict__ eb1,
                            const float* __restrict__ ew2t, const float* __restrict__ eb2,
                            const float* __restrict__ ew3, const float* __restrict__ eb3,
                            float* __restrict__ agg) {
    int e = blockIdx.x * blockDim.x + threadIdx.x;
    int s = src_idx[e];
    int d = dst_idx[e];

    float xs[5], xd[5];
#pragma unroll
    for (int j = 0; j < 5; j++) xs[j] = xw[s * 5 + j];
#pragma unroll
    for (int j = 0; j < 5; j++) xd[j] = xw[d * 5 + j];

    float ea[5];
#pragma unroll
    for (int j = 0; j < 5; j++) ea[j] = edge_attr[e * 5 + j];

    float ein[11];
    ein[0] = xd[0] - xs[0];
    ein[1] = xd[1] - xs[1];
    ein[2] = xd[2] - xs[2];
    ein[3] = sqrtf(ein[0] * ein[0] + ein[1] * ein[1] + ein[2] * ein[2]);
#pragma unroll
    for (int j = 0; j < 5; j++) ein[4 + j] = ea[j];
    ein[9] = xs[4];
    ein[10] = xd[4];

    // layer 1: 11 -> 64 (fully unrolled; j-inner contiguous weight reads)
    float h1[64];
#pragma unroll
    for (int j = 0; j < 64; j++) h1[j] = eb1[j];
#pragma unroll
    for (int k = 0; k < 11; k++) {
#pragma unroll
        for (int j = 0; j < 64; j++) h1[j] = fmaf(ein[k], ew1[k * 64 + j], h1[j]);
    }
#pragma unroll
    for (int j = 0; j < 64; j++) h1[j] = relu_f(h1[j]);

    // layer 2 (64->64, rolled over output k, ew2t row contiguous) fused with
    // layer 3 (64->5) scatter: no h2 register array, no dynamic indexing.
    float o[5];
#pragma unroll
    for (int m = 0; m < 5; m++) o[m] = eb3[m];
    for (int k = 0; k < 64; k++) {
        float a = eb2[k];
#pragma unroll
        for (int q = 0; q < 64; q++) a = fmaf(h1[q], ew2t[k * 64 + q], a);
        a = relu_f(a);
#pragma unroll
        for (int m = 0; m < 5; m++) o[m] = fmaf(a, ew3[k * 5 + m], o[m]);
    }

#pragma unroll
    for (int m = 0; m < 5; m++) {
        atomicAdd(&agg[d * 5 + m], ea[m] + o[m]);
    }
}

// NodeModel: agg/count -> MLP 7->64->64->1 -> dphi; x update; re-zero agg.
__global__ void node_kernel(float* __restrict__ xw, float* __restrict__ agg,
                            const float* __restrict__ counts,
                            const float* __restrict__ nw1, const float* __restrict__ nb1,
                            const float* __restrict__ nw2t, const float* __restrict__ nb2,
                            const float* __restrict__ nw3, const float* __restrict__ nb3) {
    int gid = blockIdx.x * blockDim.x + threadIdx.x;
    int i = min(gid, NN - 1);  // clamp: keep weight loads in uniform flow
    bool valid = (gid < NN);

    float cnt = fmaxf(counts[i], 1.0f);
    float nin[7];
    nin[0] = xw[i * 5 + 3];
    nin[1] = xw[i * 5 + 4];
#pragma unroll
    for (int m = 0; m < 5; m++) nin[2 + m] = agg[i * 5 + m] / cnt;

    float h1[64];
#pragma unroll
    for (int j = 0; j < 64; j++) h1[j] = nb1[j];
#pragma unroll
    for (int k = 0; k < 7; k++) {
#pragma unroll
        for (int j = 0; j < 64; j++) h1[j] = fmaf(nin[k], nw1[k * 64 + j], h1[j]);
    }
#pragma unroll
    for (int j = 0; j < 64; j++) h1[j] = relu_f(h1[j]);

    float dphi = nb3[0];
    for (int k = 0; k < 64; k++) {
        float a = nb2[k];
#pragma unroll
        for (int q = 0; q < 64; q++) a = fmaf(h1[q], nw2t[k * 64 + q], a);
        dphi = fmaf(relu_f(a), nw3[k], dphi);
    }

    if (valid) {
        float xv[5];
#pragma unroll
        for (int m = 0; m < 5; m++) xv[m] = xw[i * 5 + m];
        xv[4] += dphi;
#pragma unroll
        for (int m = 0; m < 5; m++) {
            float t = xv[m];
            xw[i * 5 + m] = t + relu_f(t);   // x = x_mut + relu(x_mut)
            agg[i * 5 + m] = 0.0f;           // re-zero for next edge pass
        }
    }
}

// Decoder: 5->64->64->64->1
__global__ void decoder_kernel(const float* __restrict__ xw,
                               const float* __restrict__ dw1, const float* __restrict__ db1,
                               const float* __restrict__ dw2t, const float* __restrict__ db2,
                               const float* __restrict__ dw3, const float* __restrict__ db3,
                               const float* __restrict__ dw4, const float* __restrict__ db4,
                               float* __restrict__ out) {
    int gid = blockIdx.x * blockDim.x + threadIdx.x;
    int i = min(gid, NN - 1);
    bool valid = (gid < NN);

    float xin[5];
#pragma unroll
    for (int m = 0; m < 5; m++) xin[m] = xw[i * 5 + m];

    float h1[64];
#pragma unroll
    for (int j = 0; j < 64; j++) h1[j] = db1[j];
#pragma unroll
    for (int k = 0; k < 5; k++) {
#pragma unroll
        for (int j = 0; j < 64; j++) h1[j] = fmaf(xin[k], dw1[k * 64 + j], h1[j]);
    }
#pragma unroll
    for (int j = 0; j < 64; j++) h1[j] = relu_f(h1[j]);

    // layer2 rolled over its output k2 (dw2t row contiguous), fused scatter
    // into layer-3 accumulator acc3[64] (static index j).
    float acc3[64];
#pragma unroll
    for (int j = 0; j < 64; j++) acc3[j] = db3[j];
    for (int k2 = 0; k2 < 64; k2++) {
        float a = db2[k2];
#pragma unroll
        for (int q = 0; q < 64; q++) a = fmaf(h1[q], dw2t[k2 * 64 + q], a);
        a = relu_f(a);
#pragma unroll
        for (int j = 0; j < 64; j++) acc3[j] = fmaf(a, dw3[k2 * 64 + j], acc3[j]);
    }

    float o = db4[0];
#pragma unroll
    for (int j = 0; j < 64; j++) o = fmaf(relu_f(acc3[j]), dw4[j], o);

    if (valid) out[gid] = o;
}

extern "C" void kernel_launch(void* const* d_in, const int* in_sizes, int n_in,
                              void* d_out, int out_size, void* d_ws, size_t ws_size,
                              hipStream_t stream) {
    const float* x         = (const float*)d_in[0];
    const float* edge_attr = (const float*)d_in[1];
    const float* ew1 = (const float*)d_in[2];
    const float* eb1 = (const float*)d_in[3];
    const float* ew2 = (const float*)d_in[4];
    const float* eb2 = (const float*)d_in[5];
    const float* ew3 = (const float*)d_in[6];
    const float* eb3 = (const float*)d_in[7];
    const float* nw1 = (const float*)d_in[8];
    const float* nb1 = (const float*)d_in[9];
    const float* nw2 = (const float*)d_in[10];
    const float* nb2 = (const float*)d_in[11];
    const float* nw3 = (const float*)d_in[12];
    const float* nb3 = (const float*)d_in[13];
    const float* dw1 = (const float*)d_in[14];
    const float* db1 = (const float*)d_in[15];
    const float* dw2 = (const float*)d_in[16];
    const float* db2 = (const float*)d_in[17];
    const float* dw3 = (const float*)d_in[18];
    const float* db3 = (const float*)d_in[19];
    const float* dw4 = (const float*)d_in[20];
    const float* db4 = (const float*)d_in[21];
    const int* edge_index = (const int*)d_in[22];
    const int* src = edge_index;            // edge_index[0, :]
    const int* dst = edge_index + NE;       // edge_index[1, :]
    float* out = (float*)d_out;

    // workspace layout (floats): xw[NN*5] | counts[NN] | agg[NN*5] | 4x 64x64 transposed
    float* xw     = (float*)d_ws;
    float* counts = xw + NN * 5;
    float* agg    = counts + NN;
    float* ew2t   = agg + NN * 5;
    float* nw2t   = ew2t + 64 * 64;
    float* dw2t   = nw2t + 64 * 64;

    transpose64<<<64, 64, 0, stream>>>(ew2, ew2t);
    transpose64<<<64, 64, 0, stream>>>(nw2, nw2t);
    transpose64<<<64, 64, 0, stream>>>(dw2, dw2t);

    init_kernel<<<(NN + 255) / 256, 256, 0, stream>>>(x, xw, counts, agg);
    count_kernel<<<NE / 256, 256, 0, stream>>>(dst, counts);

    for (int it = 0; it < 2; it++) {
        edge_kernel<<<NE / 256, 256, 0, stream>>>(xw, edge_attr, src, dst,
                                                  ew1, eb1, ew2t, eb2, ew3, eb3, agg);
        node_kernel<<<(NN + 255) / 256, 256, 0, stream>>>(xw, agg, counts,
                                                          nw1, nb1, nw2t, nb2, nw3, nb3);
    }

    decoder_kernel<<<(NN + 255) / 256, 256, 0, stream>>>(xw, dw1, db1, dw2t, db2,
                                                         dw3, db3, dw4, db4, out);
}